// Round 1
// baseline (1402.408 us; speedup 1.0000x reference)
//
#include <hip/hip_runtime.h>
#include <hip/hip_bf16.h>

#define NROWS 12288
#define DIM   512
#define KNBR  10
#define BM    64
#define BN    64
#define BK    32

typedef __attribute__((ext_vector_type(8))) short s16x8;
typedef __attribute__((ext_vector_type(4))) float f32x4;

static __device__ __forceinline__ unsigned short f2bf(float x) {
    __hip_bfloat16 b = __float2bfloat16(x);
    return *reinterpret_cast<unsigned short*>(&b);
}

// Stable top-k insert: keeps list sorted by (value desc, index asc).
// All indices compile-time constant after unroll -> stays in registers.
#define TOPK_INSERT(TV, TI, V, IDX)                                              \
  do {                                                                           \
    float _v = (V); int _i = (IDX);                                              \
    if (_v > TV[9] || (_v == TV[9] && _i < TI[9])) {                             \
      TV[9] = _v; TI[9] = _i;                                                    \
      _Pragma("unroll")                                                          \
      for (int _s = 9; _s > 0; --_s) {                                           \
        bool _sw = (TV[_s] > TV[_s-1]) ||                                        \
                   (TV[_s] == TV[_s-1] && TI[_s] < TI[_s-1]);                    \
        if (_sw) {                                                               \
          float _tf = TV[_s]; TV[_s] = TV[_s-1]; TV[_s-1] = _tf;                 \
          int   _ti = TI[_s]; TI[_s] = TI[_s-1]; TI[_s-1] = _ti;                 \
        }                                                                        \
      }                                                                          \
    }                                                                            \
  } while (0)

// Kernel 1: per-row squared norm (fp32) + bf16 conversion of features.
// block = 256 (4 waves), one wave per row.
__global__ __launch_bounds__(256) void prep_kernel(
    const float* __restrict__ f, float* __restrict__ sq,
    unsigned short* __restrict__ fbf) {
  const int wid = threadIdx.x >> 6;
  const int lane = threadIdx.x & 63;
  const int row = blockIdx.x * 4 + wid;
  const float4* fr = (const float4*)(f + (size_t)row * DIM);
  ushort4* br = (ushort4*)(fbf + (size_t)row * DIM);
  float s = 0.f;
#pragma unroll
  for (int u = 0; u < 2; ++u) {
    float4 v = fr[u * 64 + lane];
    s += v.x * v.x + v.y * v.y + v.z * v.z + v.w * v.w;
    ushort4 h;
    h.x = f2bf(v.x); h.y = f2bf(v.y); h.z = f2bf(v.z); h.w = f2bf(v.w);
    br[u * 64 + lane] = h;
  }
#pragma unroll
  for (int off = 32; off; off >>= 1) s += __shfl_down(s, off);
  if (lane == 0) sq[row] = s;
}

// Kernel 2: fused Gram(bf16 MFMA) -> sim -> stable per-row top-10 -> adjacency.
// One block owns BM=64 rows; loops over all 192 column tiles of BN=64.
__global__ __launch_bounds__(256) void knn_kernel(
    const unsigned short* __restrict__ fbf, const float* __restrict__ sq,
    float* __restrict__ out) {
  __shared__ short aT[BM][BK];
  __shared__ short bT[BN][BK];
  __shared__ float simf[5120];   // sim tile [64][65] (4160) / merge buf [64*80]
  __shared__ float sqrow[BM];

  const int t = threadIdx.x;
  const int lane = t & 63, wid = t >> 6;
  const int wr = wid >> 1, wc = wid & 1;      // wave -> 32x32 quadrant
  const int fr = lane & 15, kg = lane >> 4;   // MFMA fragment coords
  const int brow = blockIdx.x * BM;

  // Zero-fill this block's output slice (harness does not re-zero d_out).
  {
    f32x4* o4 = (f32x4*)(out + (size_t)brow * NROWS);
    const int total4 = BM * NROWS / 4;
    f32x4 z; z[0] = 0.f; z[1] = 0.f; z[2] = 0.f; z[3] = 0.f;
    for (int i = t; i < total4; i += 256) o4[i] = z;
  }
  if (t < BM) sqrow[t] = sq[brow + t];

  // Per-thread partial top-10: thread (lane=row, wid=column-sub-slice).
  float tv[10]; int ti[10];
#pragma unroll
  for (int s = 0; s < 10; ++s) { tv[s] = -INFINITY; ti[s] = 0x7fffffff; }

  const int sstage_r = t >> 2;             // staging: 4 threads/row
  const int sstage_k = (t & 3) * 8;        // 8 bf16 (16B) each

  for (int ct = 0; ct < NROWS / BN; ++ct) {
    const int bcol = ct * BN;
    f32x4 acc[2][2];
#pragma unroll
    for (int m = 0; m < 2; ++m)
#pragma unroll
      for (int n = 0; n < 2; ++n)
#pragma unroll
        for (int q = 0; q < 4; ++q) acc[m][n][q] = 0.f;

    for (int kt = 0; kt < DIM; kt += BK) {
      // Stage A (rows) and B^T (cols) tiles, [64][32] bf16 each.
      *(s16x8*)&aT[sstage_r][sstage_k] =
          *(const s16x8*)&fbf[(size_t)(brow + sstage_r) * DIM + kt + sstage_k];
      *(s16x8*)&bT[sstage_r][sstage_k] =
          *(const s16x8*)&fbf[(size_t)(bcol + sstage_r) * DIM + kt + sstage_k];
      __syncthreads();
      s16x8 a0 = *(const s16x8*)&aT[wr * 32 + fr][kg * 8];
      s16x8 a1 = *(const s16x8*)&aT[wr * 32 + 16 + fr][kg * 8];
      s16x8 b0 = *(const s16x8*)&bT[wc * 32 + fr][kg * 8];
      s16x8 b1 = *(const s16x8*)&bT[wc * 32 + 16 + fr][kg * 8];
      acc[0][0] = __builtin_amdgcn_mfma_f32_16x16x32_bf16(a0, b0, acc[0][0], 0, 0, 0);
      acc[0][1] = __builtin_amdgcn_mfma_f32_16x16x32_bf16(a0, b1, acc[0][1], 0, 0, 0);
      acc[1][0] = __builtin_amdgcn_mfma_f32_16x16x32_bf16(a1, b0, acc[1][0], 0, 0, 0);
      acc[1][1] = __builtin_amdgcn_mfma_f32_16x16x32_bf16(a1, b1, acc[1][1], 0, 0, 0);
      __syncthreads();
    }

    // dist -> sim, write tile to LDS. C/D layout: col=lane&15, row=(lane>>4)*4+q.
#pragma unroll
    for (int m = 0; m < 2; ++m)
#pragma unroll
      for (int n = 0; n < 2; ++n)
#pragma unroll
        for (int q = 0; q < 4; ++q) {
          int rl = wr * 32 + m * 16 + kg * 4 + q;
          int cl = wc * 32 + n * 16 + fr;
          int grow = brow + rl, gcol = bcol + cl;
          float dot = acc[m][n][q];
          float dist = sqrow[rl] + sq[gcol] - 2.0f * dot;
          float sv = (grow == gcol) ? 0.0f : __expf(-fmaxf(dist, 0.0f));
          simf[rl * 65 + cl] = sv;
        }
    __syncthreads();

    // Scan: wave `wid` scans 16-col sub-slice of each of the 64 rows (row = lane).
    {
      const int c0 = wid * 16;
#pragma unroll
      for (int c = 0; c < 16; ++c) {
        float v = simf[lane * 65 + c0 + c];
        TOPK_INSERT(tv, ti, v, bcol + c0 + c);
      }
    }
    __syncthreads();
  }

  // Dump 4 partial lists per row to LDS, then one thread per row merges.
#pragma unroll
  for (int s = 0; s < 10; ++s) {
    simf[(lane * 4 + wid) * 20 + s * 2]     = tv[s];
    simf[(lane * 4 + wid) * 20 + s * 2 + 1] = __int_as_float(ti[s]);
  }
  __syncthreads();
  if (t < BM) {
    float mv[10]; int mi[10];
#pragma unroll
    for (int s = 0; s < 10; ++s) { mv[s] = -INFINITY; mi[s] = 0x7fffffff; }
#pragma unroll
    for (int p = 0; p < 4; ++p)
#pragma unroll
      for (int s = 0; s < 10; ++s) {
        float v = simf[(t * 4 + p) * 20 + s * 2];
        int idx = __float_as_int(simf[(t * 4 + p) * 20 + s * 2 + 1]);
        TOPK_INSERT(mv, mi, v, idx);
      }
    float* orow = out + (size_t)(brow + t) * NROWS;
#pragma unroll
    for (int s = 0; s < 10; ++s) orow[mi[s]] = 1.0f;
  }
}

extern "C" void kernel_launch(void* const* d_in, const int* in_sizes, int n_in,
                              void* d_out, int out_size, void* d_ws, size_t ws_size,
                              hipStream_t stream) {
  const float* f = (const float*)d_in[0];
  float* out = (float*)d_out;
  float* sq = (float*)d_ws;
  unsigned short* fbf = (unsigned short*)((char*)d_ws + (size_t)NROWS * sizeof(float));
  const size_t need = (size_t)NROWS * sizeof(float) + (size_t)NROWS * DIM * sizeof(unsigned short);
  if (ws_size < need) return;  // fail loudly via validation rather than corrupt

  prep_kernel<<<NROWS / 4, 256, 0, stream>>>(f, sq, fbf);
  knn_kernel<<<NROWS / BM, 256, 0, stream>>>(fbf, sq, out);
}